// Round 1
// baseline (668.011 us; speedup 1.0000x reference)
//
#include <hip/hip_runtime.h>

typedef unsigned short u16;
typedef unsigned int   u32;
typedef __bf16 bf16x8 __attribute__((ext_vector_type(8)));
typedef float  f32x4  __attribute__((ext_vector_type(4)));

// ---------- helpers ----------
__device__ __forceinline__ float bf2f(u16 v){ u32 u = ((u32)v) << 16; float f; __builtin_memcpy(&f,&u,4); return f; }
__device__ __forceinline__ u16 f2bf(float f){ u32 u; __builtin_memcpy(&u,&f,4); u32 r = (u + 0x7FFFu + ((u>>16)&1u)) >> 16; return (u16)r; }
__device__ __forceinline__ float silu(float v){ return v / (1.f + __expf(-v)); }

__device__ __forceinline__ void gload_lds16(const u16* g, u16* l){
  __builtin_amdgcn_global_load_lds((const __attribute__((address_space(1))) void*)g,
                                   (__attribute__((address_space(3))) void*)l, 16, 0, 0);
}

#define FENCE asm volatile("" ::: "memory")
#define BARRIER do{ FENCE; __builtin_amdgcn_s_barrier(); FENCE; }while(0)

// Geometry: B=16, C1=128, C2=256, H=W=128, padded spatial 130x130 (1-px zero halo)
#define HP 130
#define XPIX 128              // channels per pixel in x_pad (bf16)
#define YPIX 256              // channels per pixel in y_pad (bf16)
#define XIMG (HP*HP*XPIX)
#define YIMG (HP*HP*YPIX)

// ---------- small prep kernels (fp32 -> bf16 boundary lives here) ----------
__global__ void prep_coef(const float* __restrict__ gamma, const float* __restrict__ beta,
                          const float* __restrict__ mean,  const float* __restrict__ var,
                          const float* __restrict__ b1, float2* __restrict__ coefA, float2* __restrict__ coefB){
  int c = threadIdx.x;
  float s = gamma[c] * rsqrtf(var[c] + 1e-5f);
  float t = beta[c] - mean[c] * s;
  coefA[c] = make_float2(s, t);
  coefB[c] = make_float2(s, b1[c] * s + t);   // fold 1x1 bias into BN shift
}

// w3p[n][k] bf16, k = (kh*3+kw)*128 + c   (matches act K-order (kh,kw,c))
__global__ void repack_w3(const float* __restrict__ w, u16* __restrict__ w3p){
  int idx = blockIdx.x*256 + threadIdx.x;        // n*1152 + k
  int n = idx / 1152, k = idx % 1152;
  int tap = k >> 7, c = k & 127;
  int kh = tap / 3, kw = tap % 3;
  w3p[idx] = f2bf(w[((n*128 + c)*3 + kh)*3 + kw]);
}

// w1p[n][k] bf16 (1x1 conv weight is already [n][c][1][1])
__global__ void repack_w1(const float* __restrict__ w, u16* __restrict__ w1p){
  int idx = blockIdx.x*256 + threadIdx.x;        // 65536 total
  w1p[idx] = f2bf(w[idx]);
}

// zero only the halo rings of x_pad and y_pad chunk buffers
__device__ __forceinline__ void halo_pix(int pi, int& hp, int& wp){
  if (pi < 130){ hp = 0; wp = pi; }
  else if (pi < 260){ hp = 129; wp = pi - 130; }
  else { int j = pi - 260; hp = 1 + (j >> 1); wp = (j & 1) ? 129 : 0; }
}
__global__ void zero_halos(u16* __restrict__ xpad, u16* __restrict__ ypad, int cimg){
  int idx = blockIdx.x*256 + threadIdx.x;
  const int NX = cimg*516*16;
  uint4 z = make_uint4(0u,0u,0u,0u);
  if (idx < NX){
    int b = idx / (516*16), rr = idx % (516*16);
    int pi = rr >> 4, cch = rr & 15, hp, wp;
    halo_pix(pi, hp, wp);
    *(uint4*)(xpad + (((size_t)b*HP + hp)*HP + wp)*XPIX + cch*8) = z;
  } else {
    idx -= NX;
    if (idx < cimg*516*32){
      int b = idx / (516*32), rr = idx % (516*32);
      int pi = rr >> 5, cch = rr & 31, hp, wp;
      halo_pix(pi, hp, wp);
      *(uint4*)(ypad + (((size_t)b*HP + hp)*HP + wp)*YPIX + cch*8) = z;
    }
  }
}

// fp32 NCHW -> padded bf16 NHWC transpose, 64x64 (c x w) tiles via LDS
__global__ __launch_bounds__(256) void transpose_x(const float* __restrict__ x, u16* __restrict__ xpad, int b0){
  __shared__ u16 s[64][66];
  const int tid = threadIdx.x, bid = blockIdx.x;
  const int ct = bid & 1, wt = (bid >> 1) & 1, row = bid >> 2;
  const int bl = row >> 7, h = row & 127;
  const int c0 = ct << 6, w0 = wt << 6;
  {
    const int lw = tid & 63, lc4 = tid >> 6;     // one wave spans one c-row (coalesced fp32)
    const size_t xb = ((size_t)(b0 + bl)*128)*16384 + (size_t)h*128 + w0 + lw;
    #pragma unroll
    for (int r = 0; r < 16; ++r){
      int c = r*4 + lc4;
      s[c][lw] = f2bf(x[xb + (size_t)(c0 + c)*16384]);
    }
  }
  __syncthreads();
  {
    const int lw = tid >> 5, lcp = (tid & 31) << 1;
    const size_t pb = ((size_t)bl*HP + h + 1)*HP;
    #pragma unroll
    for (int r = 0; r < 8; ++r){
      int w = r*8 + lw;
      u32 v = (u32)s[lcp][w] | ((u32)s[lcp+1][w] << 16);
      *(u32*)(xpad + (pb + (w0 + w + 1))*XPIX + c0 + lcp) = v;
    }
  }
}

// ---------- stage A: conv3x3 implicit GEMM, 256x256 tile, BK=64, 8-phase schedule ----------
// LDS tiles: sA[par][p=256][k=64], sB[par][n=256][k=64], bf16, T2 XOR-swizzled
// (chunk ^= row&7 on 16B chunks; applied via pre-swizzled GLOBAL source, linear LDS dest).
//
// Half-tile staging regions (16KB each, 2 global_load_lds / thread), chosen so each is
// DEAD (fully consumed into registers) before the phase that overwrites it:
//   h0 = A rows {0-63,128-191}   (read only at q0)      staged at q1 of T-2
//   h1 = B rows n%64<32          (read only at q0)      staged at q2 of T-2
//   h2 = B rows n%64>=32         (read q1, kept in regs for q2)  staged at q3 of T-2
//   h3 = A rows {64-127,192-255} (read only at q2)      staged at q0 of T-1
// vmcnt(6) once per K-tile (3 half-tiles in flight) -> next tile fully landed at its q0.

__device__ __forceinline__ void stageA(u16* dst, const u16* ximg, int h0, int Ts, int ho, int t){
  const int tap = Ts >> 1, cc = (Ts & 1) << 6;
  const int kh = tap / 3, kw = tap - kh*3;
  const int lc = t & 7;
  #pragma unroll
  for (int q = 0; q < 2; ++q){
    const int r = ((t >> 6) << 4) + (q << 3) + ((t >> 3) & 7);
    const int p = (ho << 6) + r + (r & 64);          // even/odd 64-row quarters
    const int hh = h0 + (p >> 7), ww = p & 127;
    const u16* src = ximg + (size_t)((hh + kh)*HP + ww + kw)*XPIX + cc + ((lc ^ (p & 7)) << 3);
    gload_lds16(src, dst + p*64 + lc*8);
  }
}

__device__ __forceinline__ void stageB3(u16* dst, const u16* w3p, int Ts, int bo, int t){
  const int lc = t & 7;
  #pragma unroll
  for (int q = 0; q < 2; ++q){
    const int r = ((t >> 6) << 4) + (q << 3) + ((t >> 3) & 7);
    const int n = ((r >> 5) << 6) + (bo << 5) + (r & 31);   // n-half quarters
    const u16* src = w3p + (size_t)n*1152 + Ts*64 + ((lc ^ (n & 7)) << 3);
    gload_lds16(src, dst + n*64 + lc*8);
  }
}

__device__ __forceinline__ bf16x8 ldfrag(const u16* s, int row, int c){
  return *(const bf16x8*)&s[row*64 + ((c ^ (row & 7)) << 3)];
}

__global__ __launch_bounds__(512, 2) void convA(const u16* __restrict__ xpad, const u16* __restrict__ w3p,
                                                const float2* __restrict__ coefA, u16* __restrict__ ypad){
  __shared__ u16 sA[2][256*64];
  __shared__ u16 sB[2][256*64];
  const int t = threadIdx.x;
  const int nwg = gridDim.x;
  const int bid = blockIdx.x;
  const int bsz = (bid & 7)*(nwg >> 3) + (bid >> 3);   // XCD-contiguous row bands (nwg%8==0)
  const int bl = bsz >> 6;
  const int h0 = (bsz & 63) << 1;                      // row pair
  const int lane = t & 63, wave = t >> 6;
  const int wm = wave & 1, wn = wave >> 1;             // 2 (M) x 4 (N) waves
  const int quad = lane >> 4, l16 = lane & 15;
  const u16* ximg = xpad + (size_t)bl * XIMG;

  f32x4 acc[8][4];
  #pragma unroll
  for (int i = 0; i < 8; ++i)
    #pragma unroll
    for (int j = 0; j < 4; ++j){ f32x4 z = {0.f,0.f,0.f,0.f}; acc[i][j] = z; }

  // prologue: T0 fully (h0,h1,h2,h3), then T1 h0-h2
  stageA (sA[0], ximg, h0, 0, 0, t);
  stageB3(sB[0], w3p,      0, 0, t);
  stageB3(sB[0], w3p,      0, 1, t);
  stageA (sA[0], ximg, h0, 0, 1, t);
  asm volatile("s_waitcnt vmcnt(4)" ::: "memory");
  stageA (sA[1], ximg, h0, 1, 0, t);
  stageB3(sB[1], w3p,      1, 0, t);
  stageB3(sB[1], w3p,      1, 1, t);
  asm volatile("s_waitcnt vmcnt(6)" ::: "memory");
  BARRIER;

  for (int T = 0; T < 18; ++T){
    const int pr = T & 1;
    const u16* A = sA[pr];
    const u16* B = sB[pr];
    bf16x8 a[4][2], b0[2][2], b1[2][2];

    // ---- q0: read A(mh0) + B(nh0); stage (T+1).h3 ----
    #pragma unroll
    for (int i = 0; i < 4; ++i){
      a[i][0] = ldfrag(A, wm*128 + i*16 + l16, quad);
      a[i][1] = ldfrag(A, wm*128 + i*16 + l16, 4 + quad);
    }
    #pragma unroll
    for (int j = 0; j < 2; ++j){
      b0[j][0] = ldfrag(B, wn*64 + j*16 + l16, quad);
      b0[j][1] = ldfrag(B, wn*64 + j*16 + l16, 4 + quad);
    }
    if (T + 1 < 18) stageA(sA[(T+1) & 1], ximg, h0, T+1, 1, t);
    BARRIER;
    __builtin_amdgcn_s_setprio(1);
    #pragma unroll
    for (int i = 0; i < 4; ++i)
      #pragma unroll
      for (int j = 0; j < 2; ++j){
        acc[i][j] = __builtin_amdgcn_mfma_f32_16x16x32_bf16(a[i][0], b0[j][0], acc[i][j], 0, 0, 0);
        acc[i][j] = __builtin_amdgcn_mfma_f32_16x16x32_bf16(a[i][1], b0[j][1], acc[i][j], 0, 0, 0);
      }
    __builtin_amdgcn_s_setprio(0);
    BARRIER;

    // ---- q1: read B(nh1); stage (T+2).h0 ----
    #pragma unroll
    for (int j = 0; j < 2; ++j){
      b1[j][0] = ldfrag(B, wn*64 + 32 + j*16 + l16, quad);
      b1[j][1] = ldfrag(B, wn*64 + 32 + j*16 + l16, 4 + quad);
    }
    if (T + 2 < 18) stageA(sA[pr], ximg, h0, T+2, 0, t);
    BARRIER;
    __builtin_amdgcn_s_setprio(1);
    #pragma unroll
    for (int i = 0; i < 4; ++i)
      #pragma unroll
      for (int j = 0; j < 2; ++j){
        acc[i][2+j] = __builtin_amdgcn_mfma_f32_16x16x32_bf16(a[i][0], b1[j][0], acc[i][2+j], 0, 0, 0);
        acc[i][2+j] = __builtin_amdgcn_mfma_f32_16x16x32_bf16(a[i][1], b1[j][1], acc[i][2+j], 0, 0, 0);
      }
    __builtin_amdgcn_s_setprio(0);
    BARRIER;

    // ---- q2: read A(mh1); stage (T+2).h1 ----
    #pragma unroll
    for (int i = 0; i < 4; ++i){
      a[i][0] = ldfrag(A, wm*128 + 64 + i*16 + l16, quad);
      a[i][1] = ldfrag(A, wm*128 + 64 + i*16 + l16, 4 + quad);
    }
    if (T + 2 < 18) stageB3(sB[pr], w3p, T+2, 0, t);
    BARRIER;
    __builtin_amdgcn_s_setprio(1);
    #pragma unroll
    for (int i = 0; i < 4; ++i)
      #pragma unroll
      for (int j = 0; j < 2; ++j){
        acc[4+i][2+j] = __builtin_amdgcn_mfma_f32_16x16x32_bf16(a[i][0], b1[j][0], acc[4+i][2+j], 0, 0, 0);
        acc[4+i][2+j] = __builtin_amdgcn_mfma_f32_16x16x32_bf16(a[i][1], b1[j][1], acc[4+i][2+j], 0, 0, 0);
      }
    __builtin_amdgcn_s_setprio(0);
    BARRIER;

    // ---- q3: no reads (b0 kept in regs); stage (T+2).h2 ----
    if (T + 2 < 18) stageB3(sB[pr], w3p, T+2, 1, t);
    BARRIER;
    __builtin_amdgcn_s_setprio(1);
    #pragma unroll
    for (int i = 0; i < 4; ++i)
      #pragma unroll
      for (int j = 0; j < 2; ++j){
        acc[4+i][j] = __builtin_amdgcn_mfma_f32_16x16x32_bf16(a[i][0], b0[j][0], acc[4+i][j], 0, 0, 0);
        acc[4+i][j] = __builtin_amdgcn_mfma_f32_16x16x32_bf16(a[i][1], b0[j][1], acc[4+i][j], 0, 0, 0);
      }
    __builtin_amdgcn_s_setprio(0);
    if (T < 16)       asm volatile("s_waitcnt vmcnt(6)" ::: "memory");
    else if (T == 16) asm volatile("s_waitcnt vmcnt(0)" ::: "memory");
    BARRIER;
  }

  // epilogue: BN + SiLU -> ypad (NHWC bf16)
  // D[p = wm*128 + ig*16 + quad*4 + r][ch = wn*64 + jg*16 + l16]
  float2 co[4];
  #pragma unroll
  for (int j = 0; j < 4; ++j) co[j] = coefA[wn*64 + j*16 + l16];
  #pragma unroll
  for (int ig = 0; ig < 8; ++ig){
    const int pb = wm*128 + ig*16 + quad*4;
    #pragma unroll
    for (int r = 0; r < 4; ++r){
      const int p = pb + r;
      const int hh = h0 + (p >> 7), ww = p & 127;
      u16* dst = ypad + ((size_t)(bl*HP + hh + 1)*HP + (ww + 1))*YPIX + wn*64;
      #pragma unroll
      for (int j = 0; j < 4; ++j){
        float v = acc[ig][j][r]*co[j].x + co[j].y;
        dst[j*16 + l16] = f2bf(silu(v));
      }
    }
  }
}

// ---------- stage B: shift + conv1x1 + bias + BN + residual + SiLU -> out (NCHW fp32) ----------
__global__ __launch_bounds__(256) void convB(const u16* __restrict__ ypad, const u16* __restrict__ w1p,
                                             const float2* __restrict__ coefB, float* __restrict__ out, int b0){
  __shared__ u16 sAct[4096];  // act [p=128][k=32]
  __shared__ u16 sW[4096];    // wts [n=128][k=32]
  const int tid = threadIdx.x;
  const int nwg = gridDim.x;
  const int bidl = (blockIdx.x & 7)*(nwg >> 3) + (blockIdx.x >> 3);  // XCD swizzle (nwg%8==0)
  const int nt = bidl & 1, row = bidl >> 1;
  const int bl = row >> 7, h = row & 127;
  const int n0 = nt << 7;
  const int lane = tid & 63, wave = tid >> 6;
  const int wc = wave & 1, wpx = wave >> 1;
  const int quad = lane >> 4, l16 = lane & 15;
  const int r0 = tid >> 2, sub = tid & 3;

  f32x4 acc[4][4];
  #pragma unroll
  for (int i = 0; i < 4; ++i)
    #pragma unroll
    for (int j = 0; j < 4; ++j){ f32x4 zz = {0.f,0.f,0.f,0.f}; acc[i][j] = zz; }

  const size_t imgy = (size_t)bl * YIMG;
  const u16* w_row0 = w1p + (size_t)(n0 + r0)*256 + sub*8;
  const u16* w_row1 = w_row0 + (size_t)64*256;

  // shift taps in padded coords: g0:y[h][w-1] g1:y[h+1][w] g2:y[h][w+1] g3:y[h-1][w]
  #pragma unroll
  for (int kt = 0; kt < 8; ++kt){
    const int g = kt >> 1;
    const int dhp = (g == 0 || g == 2) ? 1 : (g == 1 ? 2 : 0);
    const int dwp = (g == 1 || g == 3) ? 1 : (g == 0 ? 0 : 2);
    const size_t rb = imgy + (size_t)((h + dhp)*HP)*YPIX + kt*32 + sub*8;
    const u16* ga0 = ypad + rb + (size_t)(r0 + dwp)*YPIX;
    const u16* ga1 = ypad + rb + (size_t)(r0 + 64 + dwp)*YPIX;
    __syncthreads();
    gload_lds16(ga0, &sAct[tid*8]);
    gload_lds16(ga1, &sAct[2048 + tid*8]);
    gload_lds16(w_row0 + kt*32, &sW[tid*8]);
    gload_lds16(w_row1 + kt*32, &sW[2048 + tid*8]);
    __syncthreads();

    bf16x8 wf[4], af[4];
    #pragma unroll
    for (int i = 0; i < 4; ++i) wf[i] = *(const bf16x8*)&sW[(wc*64 + i*16 + l16)*32 + quad*8];
    #pragma unroll
    for (int j = 0; j < 4; ++j) af[j] = *(const bf16x8*)&sAct[(wpx*64 + j*16 + l16)*32 + quad*8];
    #pragma unroll
    for (int i = 0; i < 4; ++i)
      #pragma unroll
      for (int j = 0; j < 4; ++j)
        acc[i][j] = __builtin_amdgcn_mfma_f32_16x16x32_bf16(wf[i], af[j], acc[i][j], 0, 0, 0);
  }

  // D[channel = n0+wc*64+i*16+quad*4+r][pixel = wpx*64+j*16+l16]
  const size_t ybase = ((size_t)(bl*HP + h + 1))*HP*YPIX;
  const size_t obase = (size_t)(b0 + bl)*256*16384 + (size_t)h*128;
  #pragma unroll
  for (int i = 0; i < 4; ++i){
    const int chb = n0 + wc*64 + i*16 + quad*4;
    const float2 c0 = coefB[chb+0], c1 = coefB[chb+1], c2 = coefB[chb+2], c3 = coefB[chb+3];
    float* ob = out + obase + (size_t)chb*16384;
    #pragma unroll
    for (int j = 0; j < 4; ++j){
      const int p = wpx*64 + j*16 + l16;
      const ushort4 rv = *(const ushort4*)&ypad[ybase + (size_t)(p + 1)*YPIX + chb];  // residual, 4 ch
      ob[p]             = silu(acc[i][j][0]*c0.x + c0.y + bf2f(rv.x));
      ob[16384 + p]     = silu(acc[i][j][1]*c1.x + c1.y + bf2f(rv.y));
      ob[2*16384 + p]   = silu(acc[i][j][2]*c2.x + c2.y + bf2f(rv.z));
      ob[3*16384 + p]   = silu(acc[i][j][3]*c3.x + c3.y + bf2f(rv.w));
    }
  }
}

// ---------- launch ----------
extern "C" void kernel_launch(void* const* d_in, const int* in_sizes, int n_in,
                              void* d_out, int out_size, void* d_ws, size_t ws_size,
                              hipStream_t stream){
  const float* x  = (const float*)d_in[0];
  const float* w3 = (const float*)d_in[1];
  const float* w1 = (const float*)d_in[2];
  const float* b1 = (const float*)d_in[3];
  const float* gm = (const float*)d_in[4];
  const float* bt = (const float*)d_in[5];
  const float* mn = (const float*)d_in[6];
  const float* vr = (const float*)d_in[7];
  float* outp = (float*)d_out;

  // workspace: small buffers first, then chunk-sized padded image buffers
  char* ws = (char*)d_ws;
  float2* coefA = (float2*)ws;                                // 2048 B
  float2* coefB = coefA + 256;                                // 2048 B
  u16*    w3p   = (u16*)(ws + 4096);                          // 589,824 B
  u16*    w1p   = (u16*)(ws + 4096 + 589824);                 // 131,072 B
  const size_t fixed = 4096 + 589824 + 131072;                // 724,992 B (16B aligned)
  // per-image: xpad 4,326,400 B + ypad 8,652,800 B = 12,979,200 B
  int cimg = 16;
  while (cimg > 1 && fixed + (size_t)cimg*12979200ull > ws_size) cimg >>= 1;
  u16* xpad = (u16*)(ws + fixed);
  u16* ypad = (u16*)(ws + fixed + (size_t)cimg*4326400ull);

  prep_coef<<<1, 256, 0, stream>>>(gm, bt, mn, vr, b1, coefA, coefB);
  repack_w3<<<1152, 256, 0, stream>>>(w3, w3p);
  repack_w1<<<256, 256, 0, stream>>>(w1, w1p);
  {
    int nthr = cimg*516*48;
    zero_halos<<<(nthr + 255)/256, 256, 0, stream>>>(xpad, ypad, cimg);
  }
  for (int b0 = 0; b0 < 16; b0 += cimg){
    transpose_x<<<4*128*cimg, 256, 0, stream>>>(x, xpad, b0);
    convA<<<64*cimg, 512, 0, stream>>>(xpad, w3p, coefA, ypad);
    convB<<<2*128*cimg, 256, 0, stream>>>(ypad, w1p, coefB, outp, b0);
  }
}